// Round 1
// baseline (433.798 us; speedup 1.0000x reference)
//
#include <hip/hip_runtime.h>

#define N_NODES 100000
#define D_FEAT 64

// Degree histogram: deg[row[e]] += 1
__global__ void deg_kernel(const int* __restrict__ row, float* __restrict__ deg, int E) {
    int i = blockIdx.x * blockDim.x + threadIdx.x;
    int stride = gridDim.x * blockDim.x;
    for (; i < E; i += stride) {
        atomicAdd(&deg[row[i]], 1.0f);
    }
}

// deg -> deg^{-1/2} (0 where deg == 0)
__global__ void dis_kernel(float* __restrict__ deg, int N) {
    int i = blockIdx.x * blockDim.x + threadIdx.x;
    if (i < N) {
        float d = deg[i];
        deg[i] = (d > 0.0f) ? rsqrtf(d) : 0.0f;
    }
}

// One lane per (edge, feature): out[row*64+d] += dis[row]*dis[col] * x[col*64+d]
__global__ void scatter_kernel(const float* __restrict__ x,
                               const int* __restrict__ row,
                               const int* __restrict__ col,
                               const float* __restrict__ dis,
                               float* __restrict__ out,
                               long long total) {
    long long i = (long long)blockIdx.x * blockDim.x + threadIdx.x;
    long long stride = (long long)gridDim.x * blockDim.x;
    for (; i < total; i += stride) {
        int e = (int)(i >> 6);
        int d = (int)(i & 63);
        int r = row[e];
        int c = col[e];
        float norm = dis[r] * dis[c];
        float v = norm * x[(long long)c * D_FEAT + d];
        atomicAdd(&out[(long long)r * D_FEAT + d], v);
    }
}

extern "C" void kernel_launch(void* const* d_in, const int* in_sizes, int n_in,
                              void* d_out, int out_size, void* d_ws, size_t ws_size,
                              hipStream_t stream) {
    const float* x  = (const float*)d_in[0];
    const int*   ei = (const int*)d_in[1];
    int E = in_sizes[1] / 2;          // edge_index is (2, E): row then col
    const int* row = ei;
    const int* col = ei + E;
    float* out = (float*)d_out;
    float* deg = (float*)d_ws;        // N_NODES floats of scratch

    hipMemsetAsync(out, 0, (size_t)out_size * sizeof(float), stream);
    hipMemsetAsync(deg, 0, (size_t)N_NODES * sizeof(float), stream);

    deg_kernel<<<2048, 256, 0, stream>>>(row, deg, E);
    dis_kernel<<<(N_NODES + 255) / 256, 256, 0, stream>>>(deg, N_NODES);

    long long total = (long long)E * D_FEAT;
    int blocks = 4096;
    scatter_kernel<<<blocks, 256, 0, stream>>>(x, row, col, deg, out, total);
}